// Round 12
// baseline (142.678 us; speedup 1.0000x reference)
//
#include <hip/hip_runtime.h>
#include <math.h>

#define BB 4
#define C 64
#define O 64
#define H 128
#define W 128
#define K2 9
#define HW (H*W)
#define NOFF 36

typedef __bf16 bf16;
typedef bf16 bf16x8 __attribute__((ext_vector_type(8)));
typedef float f32x4 __attribute__((ext_vector_type(4)));
typedef unsigned short u16x8 __attribute__((ext_vector_type(8)));
typedef unsigned int u32x4 __attribute__((ext_vector_type(4)));

#define BSTR 55          /* bufF row stride (fp32 conv outputs) */
#define B2STR 19         /* packed-param row stride in uint4 (16B) units */
#define VSTR 36          /* valF row stride (fp32, 16B-aligned) */
#define SMEM_BYTES 9728  /* max(stage 6528, bufF 7040, buf2 9728, valF 9216) */
                         /* -> 16 blocks/CU x 2 waves = 32 waves/CU (max) */
#define WFRAG 18432      /* bf16 per conv-half / group: 9*4*64*8 */
#define NW_TOTAL 73728

__device__ inline unsigned short f2h_bits(float f) {
  _Float16 h = (_Float16)f;
  return __builtin_bit_cast(unsigned short, h);
}
__device__ inline float h2f(unsigned short u) {
  return (float)__builtin_bit_cast(_Float16, u);
}

// ---------------------------------------------------------------------------
// K1 (validated R6-R11): NCHW fp32 -> NHWC bf16 transpose (1024 blocks) +
// weight swizzle to MFMA a-frag order (first 288 blocks).
//  frag[(ph*9+kk)*4+to][lane][j] = Wrow[m=to*16+(lane&15)][u=kk*32+(lane>>4)*8+j]
//  K order u = tap*32 + c'.  wfC: m<36 w_off, m<54 w_mask, else 0.
// ---------------------------------------------------------------------------
__global__ __launch_bounds__(256) void prep_all(
    const float* __restrict__ x, const float* __restrict__ w_main,
    const float* __restrict__ w_off, const float* __restrict__ w_mask,
    unsigned short* __restrict__ xT16, bf16* __restrict__ wfC,
    bf16* __restrict__ wfM) {
  __shared__ float tile[64][68];
  int tid = threadIdx.x;
  int b = blockIdx.x >> 8;
  int p0 = (blockIdx.x & 255) * 64;
#pragma unroll
  for (int it = 0; it < 4; ++it) {
    int c = it * 16 + (tid >> 4);
    int p4 = (tid & 15) * 4;
    *(f32x4*)&tile[c][p4] =
        *(const f32x4*)(x + (size_t)(b * C + c) * HW + p0 + p4);
  }
  __syncthreads();
#pragma unroll
  for (int it = 0; it < 2; ++it) {
    int t = it * 256 + tid;
    int p = t >> 3;
    int h8 = t & 7;
    u16x8 o;
#pragma unroll
    for (int j = 0; j < 8; ++j) {
      bf16 v = (bf16)tile[h8 * 8 + j][p];
      o[j] = __builtin_bit_cast(unsigned short, v);
    }
    *(u16x8*)&xT16[(size_t)(b * HW + p0 + p) * C + h8 * 8] = o;
  }
  int i = blockIdx.x * 256 + tid;
  if (i < NW_TOTAL) {
    int which = (i >= 36864);
    int ii = which ? i - 36864 : i;
    int j = ii & 7;
    int l = (ii >> 3) & 63;
    int rest = ii >> 9;
    int to = rest & 3;
    int kk = (rest >> 2) % 9;
    int ph = (rest >> 2) / 9;
    int m = to * 16 + (l & 15);
    int u = kk * 32 + (l >> 4) * 8 + j;
    int tap = u >> 5;
    int c1 = u & 31;
    if (!which) {
      int c = ph * 32 + c1;
      float v = (m < NOFF) ? w_off[(m * C + c) * K2 + tap]
                : (m < 54) ? w_mask[((m - NOFF) * C + c) * K2 + tap]
                           : 0.f;
      wfC[ii] = (bf16)v;
    } else {
      wfM[ii] = (bf16)w_main[(m * C + ph * 32 + c1) * K2 + tap];
    }
  }
}

// ---------------------------------------------------------------------------
// K2: fused deform, 32-px tiles, 128-thread blocks (2 waves), 2048 blocks.
// Same structure as R11 (direct-stage conv, barrier-free in-register main
// gather) but: grid now supplies 8 blocks/CU, LDS 9,728 B allows 16, so
// occupancy is wave-capped at 32 waves/CU -- 2x R11's latency-hiding.
// __launch_bounds__(128,8) -> VGPR cap 64 (R11 shape used 56).
// Wave wv owns pixels [wv*16, wv*16+16) of the 32-px tile.
// mfma_f32_16x16x32_bf16 layouts (m89/m120 verified):
//   A: lane holds A[m=lane&15][k=(lane>>4)*8+j]
//   B: lane holds B[k=(lane>>4)*8+j][n=lane&15]
//   D: reg r holds D[m=(lane>>4)*4+r][n=lane&15]
// ---------------------------------------------------------------------------
__global__ __launch_bounds__(128, 8) void fused_deform(
    const bf16* __restrict__ xT, const bf16* __restrict__ wfC,
    const bf16* __restrict__ wfM, const float* __restrict__ b_off,
    const float* __restrict__ b_mask, float* __restrict__ out) {
  __shared__ __align__(16) char smem[SMEM_BYTES];
  bf16x8* stage16 = (bf16x8*)smem;        // [3][34][4] 16B = 6,528 (conv)
  const bf16* stageb = (const bf16*)smem;
  float* bufF = (float*)smem;             // [32][55] fp32 = 7,040 (conv out)
  u32x4* buf2 = (u32x4*)smem;             // [32][19] uint4 = 9,728 (params)
  float* valF = (float*)smem;             // [64][36] fp32 = 9,216 (out xpose)

  const int tid = threadIdx.x;
  const int lane = tid & 63;
  const int wv = tid >> 6;        // 0..1
  const int n16 = lane & 15;
  const int q4 = lane >> 4;
  const int row = wv * 16 + n16;  // this lane's pixel, 0..31

  // XCD-aware swizzle: XCD (blockIdx%8) works one image (2 MB bf16 in L2).
  const int g8 = blockIdx.x & 7;
  const int slot = blockIdx.x >> 3;         // 0..255
  const int b = g8 >> 1;
  const int ti = (g8 & 1) * 256 + slot;     // 0..511: 32-px tile index
  const int h0 = ti >> 2;
  const int w0 = (ti & 3) * 32;
  const bf16* xb = xT + (size_t)b * HW * C;

  bf16x8 zero8;
#pragma unroll
  for (int j = 0; j < 8; ++j) zero8[j] = (bf16)0.f;

  // ============ conv: 2 c-halves; MFMA straight from stage ============
  f32x4 accC[4] = {{0.f,0.f,0.f,0.f},{0.f,0.f,0.f,0.f},
                   {0.f,0.f,0.f,0.f},{0.f,0.f,0.f,0.f}};
#pragma unroll 1
  for (int ph = 0; ph < 2; ++ph) {
    if (ph) __syncthreads();  // stage reuse vs ph0 MFMA readers
#pragma unroll
    for (int it = 0; it < 4; ++it) {  // stage 3x34 window, this half's 32 ch
      int id = it * 128 + tid;
      if (id < 408) {
        int q2 = id & 3;
        int wp = (id >> 2) % 34;
        int r = (id >> 2) / 34;
        int yy = h0 + r - 1;
        int xx = w0 + wp - 1;
        bf16x8 v = zero8;
        if ((unsigned)yy < (unsigned)H && (unsigned)xx < (unsigned)W)
          v = *(const bf16x8*)(xb + (size_t)((yy << 7) + xx) * C + ph * 32 + q2 * 8);
        stage16[id] = v;
      }
    }
    __syncthreads();
    const bf16* wb = wfC + (size_t)ph * WFRAG;
#pragma unroll
    for (int kk = 0; kk < 9; ++kk) {
      bf16x8 bfr = *(const bf16x8*)(stageb +
          (size_t)(((kk / 3) * 34 + row + kk % 3) * 4 + q4) * 8);
#pragma unroll
      for (int to = 0; to < 4; ++to) {
        bf16x8 afr = *(const bf16x8*)(wb + (size_t)((kk * 4 + to) * 64 + lane) * 8);
        accC[to] = __builtin_amdgcn_mfma_f32_16x16x32_bf16(afr, bfr, accC[to], 0, 0, 0);
      }
    }
  }
  __syncthreads();  // all stage readers done before bufF overwrites it

  // conv epilogue: bias + sigmoid -> bufF[p][o]
  {
#pragma unroll
    for (int to = 0; to < 4; ++to)
#pragma unroll
      for (int r = 0; r < 4; ++r) {
        int o = to * 16 + q4 * 4 + r;
        float a = accC[to][r];
        if (o < NOFF) {
          bufF[row * BSTR + o] = a + b_off[o];
        } else if (o < 54) {
          float s = a + b_mask[o - NOFF];
          bufF[row * BSTR + o] = 1.f / (1.f + __expf(-s));
        }
      }
  }
  __syncthreads();

  // -------- bilinear precompute: 576 (p,gk) tasks -> packed uint4 --------
  unsigned int rW0[5], rW1[5], rCo[5];
#pragma unroll
  for (int it = 0; it < 5; ++it) {
    int t = it * 128 + tid;
    if (t < 576) {
      int p = t & 31;
      int gk = t >> 5;
      int g = gk / 9, tap = gk % 9;
      float offy = bufF[p * BSTR + 2 * gk];
      float offx = bufF[p * BSTR + 2 * gk + 1];
      float m = bufF[p * BSTR + NOFF + gk];
      float py = offy + (float)(h0 + tap / 3 - 1);
      float px = offx + (float)(w0 + p + tap % 3 - 1);
      float y0f = floorf(py), x0f = floorf(px);
      float wy1 = py - y0f, wx1 = px - x0f;
      float wy0 = 1.f - wy1, wx0 = 1.f - wx1;
      int y0 = (int)y0f, x0 = (int)x0f;
      int y1 = y0 + 1, x1 = x0 + 1;
      bool y0ok = (unsigned)y0 < (unsigned)H, y1ok = (unsigned)y1 < (unsigned)H;
      bool x0ok = (unsigned)x0 < (unsigned)W, x1ok = (unsigned)x1 < (unsigned)W;
      float w00 = (y0ok && x0ok) ? wy0 * wx0 * m : 0.f;
      float w01 = (y0ok && x1ok) ? wy0 * wx1 * m : 0.f;
      float w10 = (y1ok && x0ok) ? wy1 * wx0 * m : 0.f;
      float w11 = (y1ok && x1ok) ? wy1 * wx1 * m : 0.f;
      unsigned int y0c = (unsigned)min(max(y0, 0), H - 1);
      unsigned int y1c = (unsigned)min(max(y1, 0), H - 1);
      unsigned int x0c = (unsigned)min(max(x0, 0), W - 1);
      unsigned int x1c = (unsigned)min(max(x1, 0), W - 1);
      rW0[it] = (unsigned)f2h_bits(w00) | ((unsigned)f2h_bits(w01) << 16);
      rW1[it] = (unsigned)f2h_bits(w10) | ((unsigned)f2h_bits(w11) << 16);
      rCo[it] = y0c | (x0c << 8) | (y1c << 16) | (x1c << 24);
    }
  }
  __syncthreads();
#pragma unroll
  for (int it = 0; it < 5; ++it) {
    int t = it * 128 + tid;
    if (t < 576) {
      int p = t & 31;
      int gk = t >> 5;
      u32x4 pk = {rW0[it], rW1[it], rCo[it], 0u};
      buf2[p * B2STR + gk] = pk;
    }
  }
  __syncthreads();

  // -------- main deform: barrier-free, B-frags gathered in-register --------
  f32x4 accM[4] = {{0.f,0.f,0.f,0.f},{0.f,0.f,0.f,0.f},
                   {0.f,0.f,0.f,0.f},{0.f,0.f,0.f,0.f}};
#pragma unroll 1
  for (int g = 0; g < 2; ++g) {
    const bf16* bb = xb + g * 32 + q4 * 8;   // this lane's 8-channel slice
    const bf16* wb = wfM + (size_t)g * WFRAG;
#pragma unroll 3
    for (int tap = 0; tap < 9; ++tap) {
      u32x4 t4 = buf2[row * B2STR + g * 9 + tap];
      float w00 = h2f(t4.x & 0xffff), w01 = h2f(t4.x >> 16);
      float w10 = h2f(t4.y & 0xffff), w11 = h2f(t4.y >> 16);
      int r0 = (int)(t4.z & 255) << 7;
      int x0 = (int)((t4.z >> 8) & 255);
      int r1 = (int)((t4.z >> 16) & 255) << 7;
      int x1 = (int)(t4.z >> 24);
      bf16x8 v00 = *(const bf16x8*)(bb + (size_t)(r0 + x0) * C);
      bf16x8 v01 = *(const bf16x8*)(bb + (size_t)(r0 + x1) * C);
      bf16x8 v10 = *(const bf16x8*)(bb + (size_t)(r1 + x0) * C);
      bf16x8 v11 = *(const bf16x8*)(bb + (size_t)(r1 + x1) * C);
      bf16x8 bfr;
#pragma unroll
      for (int j = 0; j < 8; ++j) {
        float v = (float)v00[j] * w00 + (float)v01[j] * w01 +
                  (float)v10[j] * w10 + (float)v11[j] * w11;
        bfr[j] = (bf16)v;
      }
#pragma unroll
      for (int to = 0; to < 4; ++to) {
        bf16x8 afr = *(const bf16x8*)(wb + (size_t)((tap * 4 + to) * 64 + lane) * 8);
        accM[to] = __builtin_amdgcn_mfma_f32_16x16x32_bf16(afr, bfr, accM[to], 0, 0, 0);
      }
    }
  }

  // -------- epilogue: LDS transpose -> coalesced NCHW dwordx4 stores -------
  __syncthreads();  // buf2 readers done before valF overwrites
  {
#pragma unroll
    for (int to = 0; to < 4; ++to)
#pragma unroll
      for (int r = 0; r < 4; ++r)
        valF[(to * 16 + q4 * 4 + r) * VSTR + row] = accM[to][r];
  }
  __syncthreads();
  {
    float* ob = out + (size_t)b * O * HW + (h0 << 7) + w0;
#pragma unroll
    for (int it = 0; it < 4; ++it) {
      int id = it * 128 + tid;
      int o = id >> 3, seg = id & 7;
      f32x4 v = *(f32x4*)&valF[o * VSTR + seg * 4];
      *(f32x4*)&ob[(size_t)o * HW + seg * 4] = v;
    }
  }
}

// ---------------------------------------------------------------------------
extern "C" void kernel_launch(void* const* d_in, const int* in_sizes, int n_in,
                              void* d_out, int out_size, void* d_ws,
                              size_t ws_size, hipStream_t stream) {
  const float* x = (const float*)d_in[0];
  const float* w_main = (const float*)d_in[1];
  const float* w_off = (const float*)d_in[2];
  const float* b_off = (const float*)d_in[3];
  const float* w_mask = (const float*)d_in[4];
  const float* b_mask = (const float*)d_in[5];
  float* out = (float*)d_out;

  unsigned short* xT16 = (unsigned short*)d_ws;     // 8,388,608 B
  bf16* wfC = (bf16*)(xT16 + (size_t)BB * HW * C);  // 73,728 B
  bf16* wfM = wfC + 36864;                          // 73,728 B

  prep_all<<<1024, 256, 0, stream>>>(x, w_main, w_off, w_mask, xT16, wfC, wfM);
  fused_deform<<<2048, 128, 0, stream>>>((const bf16*)xT16, wfC, wfM, b_off,
                                         b_mask, out);
}

// Round 13
// 115.811 us; speedup vs baseline: 1.2320x; 1.2320x over previous
//
#include <hip/hip_runtime.h>
#include <math.h>

#define BB 4
#define C 64
#define O 64
#define H 128
#define W 128
#define K2 9
#define HW (H*W)
#define NOFF 36

typedef __bf16 bf16;
typedef bf16 bf16x8 __attribute__((ext_vector_type(8)));
typedef float f32x4 __attribute__((ext_vector_type(4)));
typedef unsigned short u16x8 __attribute__((ext_vector_type(8)));
typedef unsigned int u32x4 __attribute__((ext_vector_type(4)));

#define BSTR 55          /* bufF row stride (fp32 conv outputs) */
#define B2STR 19         /* packed-param row stride in uint4 units */
#define VSTR 36          /* valF row stride (fp32) */
#define SSTR 72          /* stage/val channel stride (bf16): 144B/px, 2-way banks */
#define VAL_OFF 14688    /* stage region size: 3*34*72*2 */
#define SMEM_BYTES 28512 /* 14688 + val 3*32*72*2=13824; 5 blocks/CU ok */
#define WFRAG 18432      /* bf16 per conv-half / group: 9*4*64*8 */
#define NW_TOTAL 73728

__device__ inline unsigned short f2h_bits(float f) {
  _Float16 h = (_Float16)f;
  return __builtin_bit_cast(unsigned short, h);
}
__device__ inline float h2f(unsigned short u) {
  return (float)__builtin_bit_cast(_Float16, u);
}

// ---------------------------------------------------------------------------
// K1 (validated R6-R12): NCHW fp32 -> NHWC bf16 transpose (1024 blocks) +
// weight swizzle to MFMA a-frag order (first 288 blocks).
//  frag[(ph*9+kk)*4+to][lane][j] = Wrow[m=to*16+(lane&15)][u=kk*32+(lane>>4)*8+j]
//  K order u = tap*32 + c'.  wfC: m<36 w_off, m<54 w_mask, else 0.
// ---------------------------------------------------------------------------
__global__ __launch_bounds__(256) void prep_all(
    const float* __restrict__ x, const float* __restrict__ w_main,
    const float* __restrict__ w_off, const float* __restrict__ w_mask,
    unsigned short* __restrict__ xT16, bf16* __restrict__ wfC,
    bf16* __restrict__ wfM) {
  __shared__ float tile[64][68];
  int tid = threadIdx.x;
  int b = blockIdx.x >> 8;
  int p0 = (blockIdx.x & 255) * 64;
#pragma unroll
  for (int it = 0; it < 4; ++it) {
    int c = it * 16 + (tid >> 4);
    int p4 = (tid & 15) * 4;
    *(f32x4*)&tile[c][p4] =
        *(const f32x4*)(x + (size_t)(b * C + c) * HW + p0 + p4);
  }
  __syncthreads();
#pragma unroll
  for (int it = 0; it < 2; ++it) {
    int t = it * 256 + tid;
    int p = t >> 3;
    int h8 = t & 7;
    u16x8 o;
#pragma unroll
    for (int j = 0; j < 8; ++j) {
      bf16 v = (bf16)tile[h8 * 8 + j][p];
      o[j] = __builtin_bit_cast(unsigned short, v);
    }
    *(u16x8*)&xT16[(size_t)(b * HW + p0 + p) * C + h8 * 8] = o;
  }
  int i = blockIdx.x * 256 + tid;
  if (i < NW_TOTAL) {
    int which = (i >= 36864);
    int ii = which ? i - 36864 : i;
    int j = ii & 7;
    int l = (ii >> 3) & 63;
    int rest = ii >> 9;
    int to = rest & 3;
    int kk = (rest >> 2) % 9;
    int ph = (rest >> 2) / 9;
    int m = to * 16 + (l & 15);
    int u = kk * 32 + (l >> 4) * 8 + j;
    int tap = u >> 5;
    int c1 = u & 31;
    if (!which) {
      int c = ph * 32 + c1;
      float v = (m < NOFF) ? w_off[(m * C + c) * K2 + tap]
                : (m < 54) ? w_mask[((m - NOFF) * C + c) * K2 + tap]
                           : 0.f;
      wfC[ii] = (bf16)v;
    } else {
      wfM[ii] = (bf16)w_main[(m * C + ph * 32 + c1) * K2 + tap];
    }
  }
}

// ---------------------------------------------------------------------------
// K2: fused deform, 32-px tiles x 256 threads (4 waves), grid 2048.
// Cooperative gather-through-LDS (R9's proven-fastest main phase), 1.25x the
// waves (launch_bounds(256,5): 5 blocks/CU = 20 waves, VGPR cap 102 -- avoids
// the unified-VGPR/AGPR squeeze that serialized R10/R12 at cap 64).
// Wave wv: n-tile nt=wv&1 (px 16nt..+15), m-tiles {2mh, 2mh+1}, mh=wv>>1.
// Conv: full-C 3x34 window staged ONCE (72-ch padded stride, 2-way banks),
// 18 uninterrupted MFMA k-steps.  Main: per 3-tap chunk each thread issues
// 12 independent corner loads (bulk MLP), lerps, writes val; MFMA from val.
// mfma_f32_16x16x32_bf16 layouts (m89/m120 verified):
//   A: lane holds A[m=lane&15][k=(lane>>4)*8+j]
//   B: lane holds B[k=(lane>>4)*8+j][n=lane&15]
//   D: reg r holds D[m=(lane>>4)*4+r][n=lane&15]
// ---------------------------------------------------------------------------
__global__ __launch_bounds__(256, 5) void fused_deform(
    const bf16* __restrict__ xT, const bf16* __restrict__ wfC,
    const bf16* __restrict__ wfM, const float* __restrict__ b_off,
    const float* __restrict__ b_mask, float* __restrict__ out) {
  __shared__ __align__(16) char smem[SMEM_BYTES];
  bf16* stage = (bf16*)smem;              // [3][34][72] bf16 = 14,688 (conv)
  float* bufF = (float*)smem;             // [32][55] fp32 = 7,040 (conv out)
  u32x4* buf2 = (u32x4*)smem;             // [32][19] uint4 = 9,728 (params)
  float* valF = (float*)smem;             // [64][36] fp32 = 9,216 (out xpose)
  bf16* val = (bf16*)(smem + VAL_OFF);    // [3][32][72] bf16 = 13,824 (main)

  const int tid = threadIdx.x;
  const int lane = tid & 63;
  const int wv = tid >> 6;        // 0..3
  const int n16 = lane & 15;
  const int q4 = lane >> 4;
  const int nt = wv & 1;          // n-tile (pixel half)
  const int mh = wv >> 1;         // m-half: to in {2mh, 2mh+1}
  const int row = nt * 16 + n16;  // this lane's pixel, 0..31
  const int pg = tid >> 3;        // gather pixel 0..31
  const int ch = tid & 7;         // gather 8-ch chunk 0..7 (abs ch = ch*8)

  // XCD-aware swizzle: XCD (blockIdx%8) works one image (2 MB bf16 in L2).
  const int g8 = blockIdx.x & 7;
  const int slot = blockIdx.x >> 3;      // 0..255
  const int b = g8 >> 1;
  const int ti = (g8 & 1) * 256 + slot;  // 0..511: 32-px tile index
  const int h0 = ti >> 2;
  const int w0 = (ti & 3) * 32;
  const bf16* xb = xT + (size_t)b * HW * C;

  bf16x8 zero8;
#pragma unroll
  for (int j = 0; j < 8; ++j) zero8[j] = (bf16)0.f;

  // ============ conv: stage full-C window once, 18 MFMA k-steps ============
#pragma unroll
  for (int it = 0; it < 4; ++it) {  // 816 = 3 rows x 34 px x 8 chunks
    int id = it * 256 + tid;
    if (id < 816) {
      int chk = id & 7;
      int rest = id >> 3;
      int wp = rest % 34;
      int r = rest / 34;
      int yy = h0 + r - 1;
      int xx = w0 + wp - 1;
      bf16x8 v = zero8;
      if ((unsigned)yy < (unsigned)H && (unsigned)xx < (unsigned)W)
        v = *(const bf16x8*)(xb + (size_t)((yy << 7) + xx) * C + chk * 8);
      *(bf16x8*)(stage + (r * 34 + wp) * SSTR + chk * 8) = v;
    }
  }
  __syncthreads();
  f32x4 accC[2] = {{0.f,0.f,0.f,0.f},{0.f,0.f,0.f,0.f}};
#pragma unroll 1
  for (int ph = 0; ph < 2; ++ph) {
#pragma unroll
    for (int kk = 0; kk < 9; ++kk) {
      bf16x8 bfr = *(const bf16x8*)(stage +
          ((kk / 3) * 34 + row + kk % 3) * SSTR + ph * 32 + q4 * 8);
#pragma unroll
      for (int i = 0; i < 2; ++i) {
        int to = 2 * mh + i;
        bf16x8 afr = *(const bf16x8*)(wfC +
            (size_t)(((ph * 9 + kk) * 4 + to) * 64 + lane) * 8);
        accC[i] = __builtin_amdgcn_mfma_f32_16x16x32_bf16(afr, bfr, accC[i], 0, 0, 0);
      }
    }
  }
  __syncthreads();  // stage readers done before bufF overwrites

  // conv epilogue: bias + sigmoid -> bufF[p][o]
#pragma unroll
  for (int i = 0; i < 2; ++i)
#pragma unroll
    for (int r = 0; r < 4; ++r) {
      int o = (2 * mh + i) * 16 + q4 * 4 + r;
      float a = accC[i][r];
      if (o < NOFF) {
        bufF[row * BSTR + o] = a + b_off[o];
      } else if (o < 54) {
        float s = a + b_mask[o - NOFF];
        bufF[row * BSTR + o] = 1.f / (1.f + __expf(-s));
      }
    }
  __syncthreads();

  // -------- bilinear precompute: 576 (p,gk) tasks -> packed uint4 --------
  unsigned int rW0[3], rW1[3], rCo[3];
#pragma unroll
  for (int it = 0; it < 3; ++it) {
    int t = it * 256 + tid;
    if (t < 576) {
      int p = t & 31;
      int gk = t >> 5;
      int g = gk / 9, tap = gk % 9;
      float offy = bufF[p * BSTR + 2 * gk];
      float offx = bufF[p * BSTR + 2 * gk + 1];
      float m = bufF[p * BSTR + NOFF + gk];
      float py = offy + (float)(h0 + tap / 3 - 1);
      float px = offx + (float)(w0 + p + tap % 3 - 1);
      float y0f = floorf(py), x0f = floorf(px);
      float wy1 = py - y0f, wx1 = px - x0f;
      float wy0 = 1.f - wy1, wx0 = 1.f - wx1;
      int y0 = (int)y0f, x0 = (int)x0f;
      int y1 = y0 + 1, x1 = x0 + 1;
      bool y0ok = (unsigned)y0 < (unsigned)H, y1ok = (unsigned)y1 < (unsigned)H;
      bool x0ok = (unsigned)x0 < (unsigned)W, x1ok = (unsigned)x1 < (unsigned)W;
      float w00 = (y0ok && x0ok) ? wy0 * wx0 * m : 0.f;
      float w01 = (y0ok && x1ok) ? wy0 * wx1 * m : 0.f;
      float w10 = (y1ok && x0ok) ? wy1 * wx0 * m : 0.f;
      float w11 = (y1ok && x1ok) ? wy1 * wx1 * m : 0.f;
      unsigned int y0c = (unsigned)min(max(y0, 0), H - 1);
      unsigned int y1c = (unsigned)min(max(y1, 0), H - 1);
      unsigned int x0c = (unsigned)min(max(x0, 0), W - 1);
      unsigned int x1c = (unsigned)min(max(x1, 0), W - 1);
      rW0[it] = (unsigned)f2h_bits(w00) | ((unsigned)f2h_bits(w01) << 16);
      rW1[it] = (unsigned)f2h_bits(w10) | ((unsigned)f2h_bits(w11) << 16);
      rCo[it] = y0c | (x0c << 8) | (y1c << 16) | (x1c << 24);
    }
  }
  __syncthreads();
#pragma unroll
  for (int it = 0; it < 3; ++it) {
    int t = it * 256 + tid;
    if (t < 576) {
      int p = t & 31;
      int gk = t >> 5;
      u32x4 pk = {rW0[it], rW1[it], rCo[it], 0u};
      buf2[p * B2STR + gk] = pk;
    }
  }
  __syncthreads();

  // -------- main deform: 3 tap-chunks, cooperative gather -> val -> MFMA ---
  f32x4 accM[2] = {{0.f,0.f,0.f,0.f},{0.f,0.f,0.f,0.f}};
  const bf16* bb = xb + ch * 8;   // this thread's 8-channel slice (abs)
  const int gg = ch >> 2;          // group of this chunk
#pragma unroll 1
  for (int kc = 0; kc < 3; ++kc) {
    if (kc) __syncthreads();  // val reuse vs previous MFMA readers
#pragma unroll
    for (int t = 0; t < 3; ++t) {  // 12 independent loads issued per thread
      int tap = kc * 3 + t;
      u32x4 t4 = buf2[pg * B2STR + gg * 9 + tap];
      float w00 = h2f(t4.x & 0xffff), w01 = h2f(t4.x >> 16);
      float w10 = h2f(t4.y & 0xffff), w11 = h2f(t4.y >> 16);
      int r0 = (int)(t4.z & 255) << 7;
      int x0 = (int)((t4.z >> 8) & 255);
      int r1 = (int)((t4.z >> 16) & 255) << 7;
      int x1 = (int)(t4.z >> 24);
      bf16x8 v00 = *(const bf16x8*)(bb + (size_t)(r0 + x0) * C);
      bf16x8 v01 = *(const bf16x8*)(bb + (size_t)(r0 + x1) * C);
      bf16x8 v10 = *(const bf16x8*)(bb + (size_t)(r1 + x0) * C);
      bf16x8 v11 = *(const bf16x8*)(bb + (size_t)(r1 + x1) * C);
      bf16x8 res;
#pragma unroll
      for (int j = 0; j < 8; ++j) {
        float v = (float)v00[j] * w00 + (float)v01[j] * w01 +
                  (float)v10[j] * w10 + (float)v11[j] * w11;
        res[j] = (bf16)v;
      }
      *(bf16x8*)(val + (t * 32 + pg) * SSTR + ch * 8) = res;
    }
    __syncthreads();
#pragma unroll
    for (int t = 0; t < 3; ++t) {
      int tap = kc * 3 + t;
#pragma unroll
      for (int g = 0; g < 2; ++g) {
        bf16x8 bfr = *(const bf16x8*)(val +
            (t * 32 + row) * SSTR + g * 32 + q4 * 8);
#pragma unroll
        for (int i = 0; i < 2; ++i) {
          int to = 2 * mh + i;
          bf16x8 afr = *(const bf16x8*)(wfM + (size_t)g * WFRAG +
              (size_t)((tap * 4 + to) * 64 + lane) * 8);
          accM[i] = __builtin_amdgcn_mfma_f32_16x16x32_bf16(afr, bfr, accM[i], 0, 0, 0);
        }
      }
    }
  }

  // -------- epilogue: LDS transpose -> coalesced NCHW dwordx4 stores -------
  __syncthreads();  // buf2/val readers done before valF overwrites
#pragma unroll
  for (int i = 0; i < 2; ++i)
#pragma unroll
    for (int r = 0; r < 4; ++r)
      valF[((2 * mh + i) * 16 + q4 * 4 + r) * VSTR + row] = accM[i][r];
  __syncthreads();
  {
    float* ob = out + (size_t)b * O * HW + (h0 << 7) + w0;
#pragma unroll
    for (int it = 0; it < 2; ++it) {
      int id = it * 256 + tid;
      int o = id >> 3, seg = id & 7;
      f32x4 v = *(f32x4*)&valF[o * VSTR + seg * 4];
      *(f32x4*)&ob[(size_t)o * HW + seg * 4] = v;
    }
  }
}

// ---------------------------------------------------------------------------
extern "C" void kernel_launch(void* const* d_in, const int* in_sizes, int n_in,
                              void* d_out, int out_size, void* d_ws,
                              size_t ws_size, hipStream_t stream) {
  const float* x = (const float*)d_in[0];
  const float* w_main = (const float*)d_in[1];
  const float* w_off = (const float*)d_in[2];
  const float* b_off = (const float*)d_in[3];
  const float* w_mask = (const float*)d_in[4];
  const float* b_mask = (const float*)d_in[5];
  float* out = (float*)d_out;

  unsigned short* xT16 = (unsigned short*)d_ws;     // 8,388,608 B
  bf16* wfC = (bf16*)(xT16 + (size_t)BB * HW * C);  // 73,728 B
  bf16* wfM = wfC + 36864;                          // 73,728 B

  prep_all<<<1024, 256, 0, stream>>>(x, w_main, w_off, w_mask, xT16, wfC, wfM);
  fused_deform<<<2048, 256, 0, stream>>>((const bf16*)xT16, wfC, wfM, b_off,
                                         b_mask, out);
}